// Round 1
// baseline (267.295 us; speedup 1.0000x reference)
//
#include <hip/hip_runtime.h>
#include <stdint.h>
#include <stddef.h>

typedef unsigned short u16;
typedef __attribute__((ext_vector_type(8))) __bf16 bf16x8;
typedef __attribute__((ext_vector_type(4))) float f32x4;

#define DEV __device__ __forceinline__

// ---- problem dims (hardcoded per reference) ----
#define BATCH 2
#define SEQ   2048
#define CDIM  1024
#define NH    16
#define KD    64
#define MROWS (BATCH * SEQ)   // 4096

DEV u16 f32_to_bf16(float f) {
  union { float f; unsigned u; } v; v.f = f;
  return (u16)((v.u + 0x7fffu + ((v.u >> 16) & 1u)) >> 16);
}
DEV float bf16_to_f32(u16 h) {
  union { unsigned u; float f; } v; v.u = ((unsigned)h) << 16;
  return v.f;
}

// ---------------- f32 -> bf16 convert ----------------
__global__ void cvt_f32_bf16(const float* __restrict__ in, u16* __restrict__ out, int n) {
  int stride = gridDim.x * blockDim.x * 4;
  for (int i = (blockIdx.x * blockDim.x + threadIdx.x) * 4; i < n; i += stride) {
    float4 v = *reinterpret_cast<const float4*>(in + i);
    ushort4 o;
    o.x = f32_to_bf16(v.x); o.y = f32_to_bf16(v.y);
    o.z = f32_to_bf16(v.z); o.w = f32_to_bf16(v.w);
    *reinterpret_cast<ushort4*>(out + i) = o;
  }
}

// ---------------- metric = (row-softmax of tril(pm)/8) @ P^T ----------------
// grid: 16 blocks (one per head), 64 threads (one per row)
__global__ void metric_kernel(const float* __restrict__ pm, float* __restrict__ metric) {
  int h = blockIdx.x;
  int i = threadIdx.x;
  __shared__ float P[64][65];
  const float* row = pm + (size_t)(h * 64 + i) * 64;
  float mx = -1e30f;
  for (int j = 0; j <= i; ++j) mx = fmaxf(mx, row[j] * 0.125f);
  float s = 0.f;
  for (int j = 0; j <= i; ++j) { float e = expf(row[j] * 0.125f - mx); P[i][j] = e; s += e; }
  float inv = 1.f / s;
  for (int j = 0; j <= i; ++j) P[i][j] *= inv;
  for (int j = i + 1; j < 64; ++j) P[i][j] = 0.f;
  __syncthreads();
  for (int j = 0; j < 64; ++j) {
    float acc = 0.f;
    #pragma unroll 8
    for (int l = 0; l < 64; ++l) acc += P[i][l] * P[j][l];
    metric[((size_t)h * 64 + i) * 64 + j] = acc;
  }
}

// ---------------- bf16 MFMA GEMM: C = A @ B^T  (A[M][K], B[N][K] row-major bf16) ----
// MODE 0: write proj layouts (C0 = proj_bnwk bf16, C1 = projT_bnkw bf16)
// MODE 1: write f32 C0[M][N]
template <int MODE>
__launch_bounds__(256)
__global__ void gemm_xwt(const u16* __restrict__ A, const u16* __restrict__ B,
                         void* __restrict__ C0, u16* __restrict__ C1,
                         int M, int N, int K) {
  __shared__ u16 As[128][40];
  __shared__ u16 Bs[128][40];
  int bm0 = blockIdx.y * 128, bn0 = blockIdx.x * 128;
  int t = threadIdx.x;
  int wave = t >> 6, lane = t & 63;
  int wr = wave >> 1, wc = wave & 1;
  int l15 = lane & 15, l4 = lane >> 4;
  f32x4 acc[4][4] = {};

  for (int k0 = 0; k0 < K; k0 += 32) {
    #pragma unroll
    for (int s = 0; s < 2; ++s) {
      int slot = t + s * 256;
      int r = slot >> 2, seg = slot & 3;
      uint4 va = *reinterpret_cast<const uint4*>(A + (size_t)(bm0 + r) * K + k0 + seg * 8);
      *reinterpret_cast<uint4*>(&As[r][seg * 8]) = va;
      uint4 vb = *reinterpret_cast<const uint4*>(B + (size_t)(bn0 + r) * K + k0 + seg * 8);
      *reinterpret_cast<uint4*>(&Bs[r][seg * 8]) = vb;
    }
    __syncthreads();
    bf16x8 af[4], bfm[4];
    #pragma unroll
    for (int m = 0; m < 4; ++m)
      af[m] = *reinterpret_cast<const bf16x8*>(&As[wr * 64 + m * 16 + l15][l4 * 8]);
    #pragma unroll
    for (int nn = 0; nn < 4; ++nn)
      bfm[nn] = *reinterpret_cast<const bf16x8*>(&Bs[wc * 64 + nn * 16 + l15][l4 * 8]);
    #pragma unroll
    for (int m = 0; m < 4; ++m)
      #pragma unroll
      for (int nn = 0; nn < 4; ++nn)
        acc[m][nn] = __builtin_amdgcn_mfma_f32_16x16x32_bf16(af[m], bfm[nn], acc[m][nn], 0, 0, 0);
    __syncthreads();
  }

  #pragma unroll
  for (int m = 0; m < 4; ++m) {
    int rbase = bm0 + wr * 64 + m * 16 + l4 * 4;
    #pragma unroll
    for (int nn = 0; nn < 4; ++nn) {
      int col = bn0 + wc * 64 + nn * 16 + l15;
      #pragma unroll
      for (int rr = 0; rr < 4; ++rr) {
        int row = rbase + rr;
        float v = acc[m][nn][rr];
        if (MODE == 0) {
          int bb = row >> 11, ww = row & 2047;
          int hh = col >> 6, kk = col & 63;
          u16 hv = f32_to_bf16(v);
          ((u16*)C0)[(((size_t)(bb * NH + hh)) * SEQ + ww) * KD + kk] = hv;
          C1[(((size_t)(bb * NH + hh)) * KD + kk) * SEQ + ww] = hv;
        } else {
          ((float*)C0)[(size_t)row * N + col] = v;
        }
      }
    }
  }
}

// ---------------- qm = proj @ metric (per head, metric symmetric) ----------------
// grid: (SEQ/32, NH, BATCH), 256 threads
__launch_bounds__(256)
__global__ void qm_kernel(const u16* __restrict__ proj, const float* __restrict__ metric,
                          u16* __restrict__ qm) {
  int w0 = blockIdx.x * 32;
  int h = blockIdx.y, bb = blockIdx.z;
  __shared__ float M[64][65];
  __shared__ float Pr[32][64];
  int t = threadIdx.x;
  for (int i = t; i < 4096; i += 256) M[i >> 6][i & 63] = metric[(size_t)h * 4096 + i];
  const u16* pp = proj + (((size_t)bb * NH + h) * SEQ + w0) * KD;
  for (int i = t; i < 2048; i += 256) Pr[i >> 6][i & 63] = bf16_to_f32(pp[i]);
  __syncthreads();
  int kk = t & 63, g = t >> 6;
  #pragma unroll
  for (int r8 = 0; r8 < 8; ++r8) {
    int r = r8 * 4 + g;
    float acc = 0.f;
    #pragma unroll
    for (int l = 0; l < 64; ++l) acc += Pr[r][l] * M[kk][l];  // M symmetric: row kk == col kk
    qm[(((size_t)bb * NH + h) * SEQ + w0 + r) * KD + kk] = f32_to_bf16(acc);
  }
}

// ---------------- causal flash attention ----------------
// grid: (SEQ/64, NH, BATCH), 256 threads = 4 waves, wave w owns q rows [q0+16w, q0+16w+16)
__launch_bounds__(256)
__global__ void attn_kernel(const u16* __restrict__ qm, const u16* __restrict__ proj,
                            const u16* __restrict__ projT, u16* __restrict__ nudged) {
  int q0 = blockIdx.x * 64;
  int h = blockIdx.y, bb = blockIdx.z;
  int t = threadIdx.x, wave = t >> 6, lane = t & 63;
  int l15 = lane & 15, l4 = lane >> 4;

  __shared__ u16 Ks[64][72];
  __shared__ u16 Vs[64][72];
  __shared__ u16 Ps[4][16][72];

  const size_t bh = (size_t)bb * NH + h;
  const u16* qmp = qm + (bh * SEQ + q0) * KD;
  const u16* kp  = proj + bh * SEQ * KD;
  const u16* vp  = projT + bh * KD * SEQ;

  // Q (=qm) fragments, held in registers for the whole block
  bf16x8 aq[2];
  #pragma unroll
  for (int kk = 0; kk < 2; ++kk)
    aq[kk] = *reinterpret_cast<const bf16x8*>(qmp + (size_t)(wave * 16 + l15) * KD + kk * 32 + l4 * 8);

  f32x4 acc_o[4] = {};
  float mrow[4] = {-1e30f, -1e30f, -1e30f, -1e30f};
  float lrow[4] = {0.f, 0.f, 0.f, 0.f};

  for (int j0 = 0; j0 <= q0; j0 += 64) {
    // stage K tile [64 kv][64 k] and V^T tile [64 d][64 kv]
    #pragma unroll
    for (int s = 0; s < 2; ++s) {
      int slot = t + s * 256;
      int r = slot >> 3, seg = slot & 7;
      uint4 vk = *reinterpret_cast<const uint4*>(kp + (size_t)(j0 + r) * KD + seg * 8);
      *reinterpret_cast<uint4*>(&Ks[r][seg * 8]) = vk;
      uint4 vv = *reinterpret_cast<const uint4*>(vp + (size_t)r * SEQ + j0 + seg * 8);
      *reinterpret_cast<uint4*>(&Vs[r][seg * 8]) = vv;
    }
    __syncthreads();

    // S = qm @ K^T  (per wave: 16 x 64)
    f32x4 s[4] = {};
    #pragma unroll
    for (int nf = 0; nf < 4; ++nf) {
      #pragma unroll
      for (int kk = 0; kk < 2; ++kk) {
        bf16x8 bk = *reinterpret_cast<const bf16x8*>(&Ks[nf * 16 + l15][kk * 32 + l4 * 8]);
        s[nf] = __builtin_amdgcn_mfma_f32_16x16x32_bf16(aq[kk], bk, s[nf], 0, 0, 0);
      }
    }
    #pragma unroll
    for (int nf = 0; nf < 4; ++nf) s[nf] *= 0.125f;

    // causal mask (only the diagonal tile needs it)
    if (j0 == q0) {
      #pragma unroll
      for (int nf = 0; nf < 4; ++nf) {
        int colg = j0 + nf * 16 + l15;
        #pragma unroll
        for (int rr = 0; rr < 4; ++rr) {
          int rowg = q0 + wave * 16 + l4 * 4 + rr;
          if (colg > rowg) s[nf][rr] = -1e30f;
        }
      }
    }

    // online softmax: row stats live per-lane for rows (l4*4 + rr)
    float pmx[4], alpha[4];
    #pragma unroll
    for (int rr = 0; rr < 4; ++rr) {
      float v = fmaxf(fmaxf(s[0][rr], s[1][rr]), fmaxf(s[2][rr], s[3][rr]));
      v = fmaxf(v, __shfl_xor(v, 1));
      v = fmaxf(v, __shfl_xor(v, 2));
      v = fmaxf(v, __shfl_xor(v, 4));
      v = fmaxf(v, __shfl_xor(v, 8));
      float mn = fmaxf(mrow[rr], v);
      alpha[rr] = __expf(mrow[rr] - mn);
      mrow[rr] = mn;
    }
    float rs[4] = {0.f, 0.f, 0.f, 0.f};
    #pragma unroll
    for (int nf = 0; nf < 4; ++nf)
      #pragma unroll
      for (int rr = 0; rr < 4; ++rr) {
        float p = __expf(s[nf][rr] - mrow[rr]);
        s[nf][rr] = p;
        rs[rr] += p;
      }
    #pragma unroll
    for (int rr = 0; rr < 4; ++rr) {
      float v = rs[rr];
      v += __shfl_xor(v, 1);
      v += __shfl_xor(v, 2);
      v += __shfl_xor(v, 4);
      v += __shfl_xor(v, 8);
      lrow[rr] = lrow[rr] * alpha[rr] + v;
    }
    #pragma unroll
    for (int df = 0; df < 4; ++df)
      #pragma unroll
      for (int rr = 0; rr < 4; ++rr)
        acc_o[df][rr] *= alpha[rr];

    // P (D-layout) -> LDS -> A-layout bf16 fragments
    #pragma unroll
    for (int nf = 0; nf < 4; ++nf)
      #pragma unroll
      for (int rr = 0; rr < 4; ++rr)
        Ps[wave][l4 * 4 + rr][nf * 16 + l15] = f32_to_bf16(s[nf][rr]);
    __syncthreads();

    bf16x8 pa[2];
    #pragma unroll
    for (int kk = 0; kk < 2; ++kk)
      pa[kk] = *reinterpret_cast<const bf16x8*>(&Ps[wave][l15][kk * 32 + l4 * 8]);
    #pragma unroll
    for (int df = 0; df < 4; ++df) {
      #pragma unroll
      for (int kk = 0; kk < 2; ++kk) {
        bf16x8 bv = *reinterpret_cast<const bf16x8*>(&Vs[df * 16 + l15][kk * 32 + l4 * 8]);
        acc_o[df] = __builtin_amdgcn_mfma_f32_16x16x32_bf16(pa[kk], bv, acc_o[df], 0, 0, 0);
      }
    }
    __syncthreads();
  }

  // epilogue: normalize and write nudged in [b*w][c] bf16 layout
  float inv[4];
  #pragma unroll
  for (int rr = 0; rr < 4; ++rr) inv[rr] = 1.f / lrow[rr];
  #pragma unroll
  for (int df = 0; df < 4; ++df) {
    int col = h * KD + df * 16 + l15;
    #pragma unroll
    for (int rr = 0; rr < 4; ++rr) {
      int row = q0 + wave * 16 + l4 * 4 + rr;
      nudged[((size_t)bb * SEQ + row) * CDIM + col] = f32_to_bf16(acc_o[df][rr] * inv[rr]);
    }
  }
}

// ---------------- host launch ----------------
extern "C" void kernel_launch(void* const* d_in, const int* in_sizes, int n_in,
                              void* d_out, int out_size, void* d_ws, size_t ws_size,
                              hipStream_t stream) {
  (void)in_sizes; (void)n_in; (void)out_size; (void)ws_size;
  const float* x      = (const float*)d_in[0];
  const float* Wproj  = (const float*)d_in[1];
  const float* premet = (const float*)d_in[2];
  const float* Wmix   = (const float*)d_in[3];

  char* w = (char*)d_ws;
  u16* x_bf   = (u16*)w;  w += (size_t)MROWS * CDIM * 2;        // 8 MB
  u16* wp_bf  = (u16*)w;  w += (size_t)CDIM * CDIM * 2;         // 2 MB
  u16* wm_bf  = (u16*)w;  w += (size_t)CDIM * CDIM * 2;         // 2 MB
  float* metric = (float*)w; w += (size_t)NH * KD * KD * 4;     // 256 KB
  u16* proj_bnwk = (u16*)w; w += (size_t)BATCH * NH * SEQ * KD * 2;  // 8 MB
  u16* projT     = (u16*)w; w += (size_t)BATCH * NH * KD * SEQ * 2;  // 8 MB
  u16* qm        = (u16*)w; w += (size_t)BATCH * NH * SEQ * KD * 2;  // 8 MB
  u16* nudged    = (u16*)w; w += (size_t)MROWS * CDIM * 2;           // 8 MB

  hipLaunchKernelGGL(cvt_f32_bf16, dim3(2048), dim3(256), 0, stream, x, x_bf, MROWS * CDIM);
  hipLaunchKernelGGL(cvt_f32_bf16, dim3(1024), dim3(256), 0, stream, Wproj, wp_bf, CDIM * CDIM);
  hipLaunchKernelGGL(cvt_f32_bf16, dim3(1024), dim3(256), 0, stream, Wmix, wm_bf, CDIM * CDIM);
  hipLaunchKernelGGL(metric_kernel, dim3(NH), dim3(64), 0, stream, premet, metric);
  hipLaunchKernelGGL((gemm_xwt<0>), dim3(CDIM / 128, MROWS / 128), dim3(256), 0, stream,
                     x_bf, wp_bf, (void*)proj_bnwk, projT, MROWS, CDIM, CDIM);
  hipLaunchKernelGGL(qm_kernel, dim3(SEQ / 32, NH, BATCH), dim3(256), 0, stream,
                     proj_bnwk, metric, qm);
  hipLaunchKernelGGL(attn_kernel, dim3(SEQ / 64, NH, BATCH), dim3(256), 0, stream,
                     qm, proj_bnwk, projT, nudged);
  hipLaunchKernelGGL((gemm_xwt<1>), dim3(CDIM / 128, MROWS / 128), dim3(256), 0, stream,
                     nudged, wm_bf, d_out, nullptr, MROWS, CDIM, CDIM);
}

// Round 2
// 259.457 us; speedup vs baseline: 1.0302x; 1.0302x over previous
//
#include <hip/hip_runtime.h>
#include <stdint.h>
#include <stddef.h>

typedef unsigned short u16;
typedef unsigned int u32;
typedef __attribute__((ext_vector_type(8))) __bf16 bf16x8;
typedef __attribute__((ext_vector_type(4))) float f32x4;
typedef __attribute__((ext_vector_type(16))) float f32x16;

#define DEV __device__ __forceinline__

// ---- problem dims (hardcoded per reference) ----
#define BATCH 2
#define SEQ   2048
#define CDIM  1024
#define NH    16
#define KD    64
#define MROWS (BATCH * SEQ)   // 4096

DEV u16 f32_to_bf16(float f) {
  union { float f; unsigned u; } v; v.f = f;
  return (u16)((v.u + 0x7fffu + ((v.u >> 16) & 1u)) >> 16);
}
DEV float bf16_to_f32(u16 h) {
  union { unsigned u; float f; } v; v.u = ((unsigned)h) << 16;
  return v.f;
}
DEV u32 pack_bf16x2(float a, float b) {
  union { __bf16 h[2]; u32 u; } r;
  r.h[0] = (__bf16)a; r.h[1] = (__bf16)b;
  return r.u;
}

// XOR swizzle (u16-index granularity of 8): spreads 16B slots across bank groups
#define SW8(r) ((((r) ^ ((r) >> 3)) & 7) << 3)

// ---------------- f32 -> bf16 convert ----------------
__global__ void cvt_f32_bf16(const float* __restrict__ in, u16* __restrict__ out, int n) {
  int stride = gridDim.x * blockDim.x * 4;
  for (int i = (blockIdx.x * blockDim.x + threadIdx.x) * 4; i < n; i += stride) {
    float4 v = *reinterpret_cast<const float4*>(in + i);
    ushort4 o;
    o.x = f32_to_bf16(v.x); o.y = f32_to_bf16(v.y);
    o.z = f32_to_bf16(v.z); o.w = f32_to_bf16(v.w);
    *reinterpret_cast<ushort4*>(out + i) = o;
  }
}

// ---------------- metric = (row-softmax of tril(pm)/8) @ P^T ----------------
__global__ void metric_kernel(const float* __restrict__ pm, float* __restrict__ metric) {
  int h = blockIdx.x;
  int i = threadIdx.x;
  __shared__ float P[64][65];
  const float* row = pm + (size_t)(h * 64 + i) * 64;
  float mx = -1e30f;
  for (int j = 0; j <= i; ++j) mx = fmaxf(mx, row[j] * 0.125f);
  float s = 0.f;
  for (int j = 0; j <= i; ++j) { float e = expf(row[j] * 0.125f - mx); P[i][j] = e; s += e; }
  float inv = 1.f / s;
  for (int j = 0; j <= i; ++j) P[i][j] *= inv;
  for (int j = i + 1; j < 64; ++j) P[i][j] = 0.f;
  __syncthreads();
  for (int j = 0; j < 64; ++j) {
    float acc = 0.f;
    #pragma unroll 8
    for (int l = 0; l < 64; ++l) acc += P[i][l] * P[j][l];
    metric[((size_t)h * 64 + i) * 64 + j] = acc;
  }
}

// ---------------- bf16 MFMA GEMM: C = A @ B^T  (A[M][K], B[N][K] row-major bf16) ----
// MODE 0: write proj_bnwk bf16;  MODE 1: write f32 C0[M][N]
template <int MODE>
__launch_bounds__(256)
__global__ void gemm_xwt(const u16* __restrict__ A, const u16* __restrict__ B,
                         void* __restrict__ C0,
                         int M, int N, int K) {
  __shared__ u16 As[128][40];
  __shared__ u16 Bs[128][40];
  int bm0 = blockIdx.y * 128, bn0 = blockIdx.x * 128;
  int t = threadIdx.x;
  int wave = t >> 6, lane = t & 63;
  int wr = wave >> 1, wc = wave & 1;
  int l15 = lane & 15, l4 = lane >> 4;
  f32x4 acc[4][4] = {};

  for (int k0 = 0; k0 < K; k0 += 32) {
    #pragma unroll
    for (int s = 0; s < 2; ++s) {
      int slot = t + s * 256;
      int r = slot >> 2, seg = slot & 3;
      uint4 va = *reinterpret_cast<const uint4*>(A + (size_t)(bm0 + r) * K + k0 + seg * 8);
      *reinterpret_cast<uint4*>(&As[r][seg * 8]) = va;
      uint4 vb = *reinterpret_cast<const uint4*>(B + (size_t)(bn0 + r) * K + k0 + seg * 8);
      *reinterpret_cast<uint4*>(&Bs[r][seg * 8]) = vb;
    }
    __syncthreads();
    bf16x8 af[4], bfm[4];
    #pragma unroll
    for (int m = 0; m < 4; ++m)
      af[m] = *reinterpret_cast<const bf16x8*>(&As[wr * 64 + m * 16 + l15][l4 * 8]);
    #pragma unroll
    for (int nn = 0; nn < 4; ++nn)
      bfm[nn] = *reinterpret_cast<const bf16x8*>(&Bs[wc * 64 + nn * 16 + l15][l4 * 8]);
    #pragma unroll
    for (int m = 0; m < 4; ++m)
      #pragma unroll
      for (int nn = 0; nn < 4; ++nn)
        acc[m][nn] = __builtin_amdgcn_mfma_f32_16x16x32_bf16(af[m], bfm[nn], acc[m][nn], 0, 0, 0);
    __syncthreads();
  }

  #pragma unroll
  for (int m = 0; m < 4; ++m) {
    int rbase = bm0 + wr * 64 + m * 16 + l4 * 4;
    #pragma unroll
    for (int nn = 0; nn < 4; ++nn) {
      int col = bn0 + wc * 64 + nn * 16 + l15;
      #pragma unroll
      for (int rr = 0; rr < 4; ++rr) {
        int row = rbase + rr;
        float v = acc[m][nn][rr];
        if (MODE == 0) {
          int bb = row >> 11, ww = row & 2047;
          int hh = col >> 6, kk = col & 63;
          ((u16*)C0)[(((size_t)(bb * NH + hh)) * SEQ + ww) * KD + kk] = f32_to_bf16(v);
        } else {
          ((float*)C0)[(size_t)row * N + col] = v;
        }
      }
    }
  }
}

// ---------------- qm = proj @ metric (per head, metric symmetric) ----------------
__launch_bounds__(256)
__global__ void qm_kernel(const u16* __restrict__ proj, const float* __restrict__ metric,
                          u16* __restrict__ qm) {
  int w0 = blockIdx.x * 32;
  int h = blockIdx.y, bb = blockIdx.z;
  __shared__ float M[64][65];
  __shared__ float Pr[32][64];
  int t = threadIdx.x;
  for (int i = t; i < 4096; i += 256) M[i >> 6][i & 63] = metric[(size_t)h * 4096 + i];
  const u16* pp = proj + (((size_t)bb * NH + h) * SEQ + w0) * KD;
  for (int i = t; i < 2048; i += 256) Pr[i >> 6][i & 63] = bf16_to_f32(pp[i]);
  __syncthreads();
  int kk = t & 63, g = t >> 6;
  #pragma unroll
  for (int r8 = 0; r8 < 8; ++r8) {
    int r = r8 * 4 + g;
    float acc = 0.f;
    #pragma unroll
    for (int l = 0; l < 64; ++l) acc += Pr[r][l] * M[kk][l];  // M symmetric
    qm[(((size_t)bb * NH + h) * SEQ + w0 + r) * KD + kk] = f32_to_bf16(acc);
  }
}

// ---------------- causal flash attention, swapped-QK 32x32 MFMA ----------------
// grid: (32 [b*h], 16 [chunk, LPT-ordered]), 256 threads = 4 warps.
// Warp w owns q rows [q0+32w, q0+32w+31]. KVBLK=64, double-buffered K + in-kernel V^T.
__launch_bounds__(256)
__global__ void attn_kernel(const u16* __restrict__ qm, const u16* __restrict__ proj,
                            u16* __restrict__ nudged) {
  const int bh = blockIdx.x;              // 0..31
  const int bb = bh >> 4, h = bh & 15;
  const int chunk = 15 - (int)blockIdx.y; // longest-first
  const int q0 = chunk * 128;
  const int t = threadIdx.x, wv = t >> 6;
  const int lane = t & 63;
  const int c = lane & 31, hi = lane >> 5;
  const int Q0w = q0 + wv * 32;
  const int qmax = Q0w + 31;
  const int q_row = Q0w + c;

  __shared__ __align__(16) u16 sm[16384];  // 32KB: K[2][64][64] + V^T[2][64][64]

  const size_t bho = (size_t)bh * SEQ * KD;
  const u16* kp = proj + bho;
  const u16* qmp = qm + bho;

  // Q fragments (held for the whole block)
  bf16x8 qf[4];
  #pragma unroll
  for (int kc = 0; kc < 4; ++kc)
    qf[kc] = *reinterpret_cast<const bf16x8*>(qmp + (size_t)(Q0w + c) * KD + kc * 16 + hi * 8);

  f32x16 o0 = {}, o1 = {};
  float mrow = -1e30f, lrow = 0.f;
  const float cl2 = 0.125f * 1.44269504088896f;   // 1/sqrt(64) * log2(e)

  const int nt = (q0 + 128) / 64;

  // prologue: stage tile 0 into buf 0 (K swizzled row-major, V^T transposed in-kernel)
  {
    #pragma unroll
    for (int s = 0; s < 2; ++s) {
      int slot = s * 256 + t, row = slot >> 3, seg = slot & 7;
      union { uint4 q4; u16 hh[8]; } v;
      v.q4 = *reinterpret_cast<const uint4*>(kp + (size_t)row * KD + seg * 8);
      *reinterpret_cast<uint4*>(sm + row * 64 + ((seg * 8) ^ SW8(row))) = v.q4;
      #pragma unroll
      for (int i = 0; i < 8; ++i) {
        int d = seg * 8 + i;
        sm[8192 + d * 64 + (row ^ SW8(d))] = v.hh[i];
      }
    }
  }
  __syncthreads();

  int buf = 0;
  for (int it = 0; it < nt; ++it) {
    const int j0 = it * 64;
    const bool pf = (it + 1 < nt);
    union { uint4 q4; u16 hh[8]; } st0, st1;
    // T14: issue next-tile global loads BEFORE compute
    if (pf) {
      const u16* knext = kp + (size_t)(j0 + 64) * KD;
      int slot0 = t, slot1 = 256 + t;
      st0.q4 = *reinterpret_cast<const uint4*>(knext + (size_t)(slot0 >> 3) * KD + (slot0 & 7) * 8);
      st1.q4 = *reinterpret_cast<const uint4*>(knext + (size_t)(slot1 >> 3) * KD + (slot1 & 7) * 8);
    }

    if (j0 <= qmax) {
      const u16* K = sm + buf * 4096;
      const u16* V = sm + 8192 + buf * 4096;
      // S^T = K @ Q^T : rows=kv, cols=q (lane c owns q-col c)
      f32x16 s0 = {}, s1 = {};
      #pragma unroll
      for (int kc = 0; kc < 4; ++kc) {
        int colb = kc * 16 + hi * 8;
        bf16x8 a0 = *reinterpret_cast<const bf16x8*>(K + (c)      * 64 + (colb ^ SW8(c)));
        bf16x8 a1 = *reinterpret_cast<const bf16x8*>(K + (c + 32) * 64 + (colb ^ SW8(c + 32)));
        s0 = __builtin_amdgcn_mfma_f32_32x32x16_bf16(a0, qf[kc], s0, 0, 0, 0);
        s1 = __builtin_amdgcn_mfma_f32_32x32x16_bf16(a1, qf[kc], s1, 0, 0, 0);
      }
      // causal mask (only tiles overlapping the warp's q range)
      if (j0 + 63 >= Q0w) {
        #pragma unroll
        for (int r = 0; r < 16; ++r) {
          int kvl = (r & 3) + 8 * (r >> 2) + 4 * hi;
          if (j0 + kvl      > q_row) s0[r] = -1e30f;
          if (j0 + 32 + kvl > q_row) s1[r] = -1e30f;
        }
      }
      // row max: in-register + one cross-half swap
      float pmax = s0[0];
      #pragma unroll
      for (int r = 1; r < 16; ++r) pmax = fmaxf(pmax, s0[r]);
      #pragma unroll
      for (int r = 0; r < 16; ++r) pmax = fmaxf(pmax, s1[r]);
      pmax = fmaxf(pmax, __shfl_xor(pmax, 32));
      // T13 defer-max: rescale only when max grew past e^4 headroom
      if (__any(pmax - mrow > 32.f)) {
        float mn = fmaxf(mrow, pmax);
        float alpha = exp2f((mrow - mn) * cl2);
        #pragma unroll
        for (int r = 0; r < 16; ++r) { o0[r] *= alpha; o1[r] *= alpha; }
        lrow *= alpha;
        mrow = mn;
      }
      const float mc = mrow * cl2;
      float rs = 0.f;
      #pragma unroll
      for (int r = 0; r < 16; ++r) { float p = exp2f(s0[r] * cl2 - mc); s0[r] = p; rs += p; }
      #pragma unroll
      for (int r = 0; r < 16; ++r) { float p = exp2f(s1[r] * cl2 - mc); s1[r] = p; rs += p; }
      rs += __shfl_xor(rs, 32);
      lrow += rs;

      // pack P to bf16 words: w[tile][q4][0]=kv(8q4+4hi)+0,1  [1]=+2,3
      u32 w[2][4][2];
      #pragma unroll
      for (int q4 = 0; q4 < 4; ++q4) {
        w[0][q4][0] = pack_bf16x2(s0[q4 * 4 + 0], s0[q4 * 4 + 1]);
        w[0][q4][1] = pack_bf16x2(s0[q4 * 4 + 2], s0[q4 * 4 + 3]);
        w[1][q4][0] = pack_bf16x2(s1[q4 * 4 + 0], s1[q4 * 4 + 1]);
        w[1][q4][1] = pack_bf16x2(s1[q4 * 4 + 2], s1[q4 * 4 + 3]);
      }
      // exchange halves: build PA fragments pa[ks] = P[q=Q0w+c][16ks+8hi+0..7]
      bf16x8 pa[4];
      #pragma unroll
      for (int tt = 0; tt < 2; ++tt) {
        #pragma unroll
        for (int j = 0; j < 2; ++j) {
          int own = 2 * j + hi, send = 2 * j + (hi ^ 1);
          u32 ra = __shfl_xor(w[tt][send][0], 32);
          u32 rb = __shfl_xor(w[tt][send][1], 32);
          union { u32 u[4]; bf16x8 v; } pk;
          if (hi == 0) { pk.u[0] = w[tt][own][0]; pk.u[1] = w[tt][own][1]; pk.u[2] = ra; pk.u[3] = rb; }
          else         { pk.u[0] = ra; pk.u[1] = rb; pk.u[2] = w[tt][own][0]; pk.u[3] = w[tt][own][1]; }
          pa[tt * 2 + j] = pk.v;
        }
      }
      // O^T += V^T @ P^T : rows=d, cols=q (stats stay lane-local)
      #pragma unroll
      for (int ks = 0; ks < 4; ++ks) {
        int colb = ks * 16 + hi * 8;
        bf16x8 v0 = *reinterpret_cast<const bf16x8*>(V + (c)      * 64 + (colb ^ SW8(c)));
        bf16x8 v1 = *reinterpret_cast<const bf16x8*>(V + (c + 32) * 64 + (colb ^ SW8(c + 32)));
        o0 = __builtin_amdgcn_mfma_f32_32x32x16_bf16(v0, pa[ks], o0, 0, 0, 0);
        o1 = __builtin_amdgcn_mfma_f32_32x32x16_bf16(v1, pa[ks], o1, 0, 0, 0);
      }
    }

    // T14: LDS writes of the prefetched tile AFTER compute
    if (pf) {
      u16* Kd = sm + (buf ^ 1) * 4096;
      u16* Vd = sm + 8192 + (buf ^ 1) * 4096;
      {
        int slot = t, row = slot >> 3, seg = slot & 7;
        *reinterpret_cast<uint4*>(Kd + row * 64 + ((seg * 8) ^ SW8(row))) = st0.q4;
        #pragma unroll
        for (int i = 0; i < 8; ++i) {
          int d = seg * 8 + i;
          Vd[d * 64 + (row ^ SW8(d))] = st0.hh[i];
        }
      }
      {
        int slot = 256 + t, row = slot >> 3, seg = slot & 7;
        *reinterpret_cast<uint4*>(Kd + row * 64 + ((seg * 8) ^ SW8(row))) = st1.q4;
        #pragma unroll
        for (int i = 0; i < 8; ++i) {
          int d = seg * 8 + i;
          Vd[d * 64 + (row ^ SW8(d))] = st1.hh[i];
        }
      }
    }
    __syncthreads();
    buf ^= 1;
  }

  // epilogue: normalize, stage O (q-major) in LDS, coalesced bf16 store
  float inv = 1.f / lrow;
  #pragma unroll
  for (int r = 0; r < 16; ++r) { o0[r] *= inv; o1[r] *= inv; }
  u32* Ob = reinterpret_cast<u32*>(sm);   // [128][33] u32 (pad -> conflict-free)
  #pragma unroll
  for (int r = 0; r < 16; r += 2) {
    int d0 = (r & 3) + 8 * (r >> 2) + 4 * hi;   // even
    int w0 = d0 >> 1;
    Ob[(wv * 32 + c) * 33 + w0]      = pack_bf16x2(o0[r], o0[r + 1]);
    Ob[(wv * 32 + c) * 33 + 16 + w0] = pack_bf16x2(o1[r], o1[r + 1]);
  }
  __syncthreads();
  {
    int row = t >> 1, half = t & 1;
    u32 tmp[16];
    #pragma unroll
    for (int i = 0; i < 16; ++i) tmp[i] = Ob[row * 33 + half * 16 + i];
    u16* dst = nudged + ((size_t)bb * SEQ + q0 + row) * CDIM + h * KD + half * 32;
    #pragma unroll
    for (int i = 0; i < 4; ++i) {
      uint4 ov; ov.x = tmp[i*4]; ov.y = tmp[i*4+1]; ov.z = tmp[i*4+2]; ov.w = tmp[i*4+3];
      *reinterpret_cast<uint4*>(dst + i * 8) = ov;
    }
  }
}

// ---------------- host launch ----------------
extern "C" void kernel_launch(void* const* d_in, const int* in_sizes, int n_in,
                              void* d_out, int out_size, void* d_ws, size_t ws_size,
                              hipStream_t stream) {
  (void)in_sizes; (void)n_in; (void)out_size; (void)ws_size;
  const float* x      = (const float*)d_in[0];
  const float* Wproj  = (const float*)d_in[1];
  const float* premet = (const float*)d_in[2];
  const float* Wmix   = (const float*)d_in[3];

  char* w = (char*)d_ws;
  u16* x_bf   = (u16*)w;  w += (size_t)MROWS * CDIM * 2;        // 8 MB
  u16* wp_bf  = (u16*)w;  w += (size_t)CDIM * CDIM * 2;         // 2 MB
  u16* wm_bf  = (u16*)w;  w += (size_t)CDIM * CDIM * 2;         // 2 MB
  float* metric = (float*)w; w += (size_t)NH * KD * KD * 4;     // 256 KB
  u16* proj_bnwk = (u16*)w; w += (size_t)BATCH * NH * SEQ * KD * 2;  // 8 MB
  u16* qm        = (u16*)w; w += (size_t)BATCH * NH * SEQ * KD * 2;  // 8 MB
  u16* nudged    = (u16*)w; w += (size_t)MROWS * CDIM * 2;           // 8 MB

  hipLaunchKernelGGL(cvt_f32_bf16, dim3(2048), dim3(256), 0, stream, x, x_bf, MROWS * CDIM);
  hipLaunchKernelGGL(cvt_f32_bf16, dim3(1024), dim3(256), 0, stream, Wproj, wp_bf, CDIM * CDIM);
  hipLaunchKernelGGL(cvt_f32_bf16, dim3(1024), dim3(256), 0, stream, Wmix, wm_bf, CDIM * CDIM);
  hipLaunchKernelGGL(metric_kernel, dim3(NH), dim3(64), 0, stream, premet, metric);
  hipLaunchKernelGGL((gemm_xwt<0>), dim3(CDIM / 128, MROWS / 128), dim3(256), 0, stream,
                     x_bf, wp_bf, (void*)proj_bnwk, MROWS, CDIM, CDIM);
  hipLaunchKernelGGL(qm_kernel, dim3(SEQ / 32, NH, BATCH), dim3(256), 0, stream,
                     proj_bnwk, metric, qm);
  hipLaunchKernelGGL(attn_kernel, dim3(32, 16), dim3(256), 0, stream,
                     qm, proj_bnwk, nudged);
  hipLaunchKernelGGL((gemm_xwt<1>), dim3(CDIM / 128, MROWS / 128), dim3(256), 0, stream,
                     nudged, wm_bf, d_out, MROWS, CDIM, CDIM);
}

// Round 3
// 244.284 us; speedup vs baseline: 1.0942x; 1.0621x over previous
//
#include <hip/hip_runtime.h>
#include <stdint.h>
#include <stddef.h>

typedef unsigned short u16;
typedef unsigned int u32;
typedef __attribute__((ext_vector_type(8))) __bf16 bf16x8;
typedef __attribute__((ext_vector_type(4))) float f32x4;
typedef __attribute__((ext_vector_type(16))) float f32x16;

#define DEV __device__ __forceinline__

// ---- problem dims (hardcoded per reference) ----
#define BATCH 2
#define SEQ   2048
#define CDIM  1024
#define NH    16
#define KD    64
#define MROWS (BATCH * SEQ)   // 4096
#define NX (MROWS * CDIM)     // 4194304
#define NW (CDIM * CDIM)      // 1048576

DEV u16 f32_to_bf16(float f) {
  union { float f; unsigned u; } v; v.f = f;
  return (u16)((v.u + 0x7fffu + ((v.u >> 16) & 1u)) >> 16);
}
DEV float bf16_to_f32(u16 h) {
  union { unsigned u; float f; } v; v.u = ((unsigned)h) << 16;
  return v.f;
}
DEV u32 pack_bf16x2(float a, float b) {
  union { __bf16 h[2]; u32 u; } r;
  r.h[0] = (__bf16)a; r.h[1] = (__bf16)b;
  return r.u;
}

// XOR swizzle in u16 units (8-granular): element (row,col) stored at col ^ SW8(row)
#define SW8(r) ((((r) ^ ((r) >> 3)) & 7) << 3)

// async global->LDS, 16B per lane, lane offset = lane*16, base must be wave-uniform
DEV void gl_lds16(const u16* g, u16* l) {
  __builtin_amdgcn_global_load_lds(
      (const __attribute__((address_space(1))) void*)(g),
      (__attribute__((address_space(3))) void*)(l), 16, 0, 0);
}

// ---------------- fused f32 -> bf16 convert (x, W_proj, W_mix) ----------------
__global__ void cvt_all(const float* __restrict__ x, const float* __restrict__ wp,
                        const float* __restrict__ wm,
                        u16* __restrict__ xb, u16* __restrict__ wpb, u16* __restrict__ wmb) {
  int total4 = (NX + 2 * NW) >> 2;
  for (int i4 = blockIdx.x * blockDim.x + threadIdx.x; i4 < total4;
       i4 += gridDim.x * blockDim.x) {
    int i = i4 << 2;
    const float* src; u16* dst; int off;
    if (i < NX)           { src = x;  dst = xb;  off = i; }
    else if (i < NX + NW) { src = wp; dst = wpb; off = i - NX; }
    else                  { src = wm; dst = wmb; off = i - NX - NW; }
    float4 v = *reinterpret_cast<const float4*>(src + off);
    ushort4 o;
    o.x = f32_to_bf16(v.x); o.y = f32_to_bf16(v.y);
    o.z = f32_to_bf16(v.z); o.w = f32_to_bf16(v.w);
    *reinterpret_cast<ushort4*>(dst + off) = o;
  }
}

// ---------------- metric = (row-softmax of tril(pm)/8) @ P^T ----------------
__global__ void metric_kernel(const float* __restrict__ pm, float* __restrict__ metric) {
  int h = blockIdx.x;
  int i = threadIdx.x;
  __shared__ float P[64][65];
  const float* row = pm + (size_t)(h * 64 + i) * 64;
  float mx = -1e30f;
  for (int j = 0; j <= i; ++j) mx = fmaxf(mx, row[j] * 0.125f);
  float s = 0.f;
  for (int j = 0; j <= i; ++j) { float e = expf(row[j] * 0.125f - mx); P[i][j] = e; s += e; }
  float inv = 1.f / s;
  for (int j = 0; j <= i; ++j) P[i][j] *= inv;
  for (int j = i + 1; j < 64; ++j) P[i][j] = 0.f;
  __syncthreads();
  for (int j = 0; j < 64; ++j) {
    float acc = 0.f;
    #pragma unroll 8
    for (int l = 0; l < 64; ++l) acc += P[i][l] * P[j][l];
    metric[((size_t)h * 64 + i) * 64 + j] = acc;
  }
}

// ---------------- bf16 MFMA GEMM: C = A @ B^T, global_load_lds staging ----------------
// MODE 0: write proj_bnwk bf16;  MODE 1: write f32 C0[M][N]
template <int MODE>
__launch_bounds__(256)
__global__ void gemm_xwt(const u16* __restrict__ A, const u16* __restrict__ B,
                         void* __restrict__ C0, int M, int N, int K) {
  __shared__ __align__(16) u16 As[128 * 32];
  __shared__ __align__(16) u16 Bs[128 * 32];
  int bm0 = blockIdx.y * 128, bn0 = blockIdx.x * 128;
  int t = threadIdx.x, wv = t >> 6, lane = t & 63;
  int wr = wv >> 1, wc = wv & 1;
  int l15 = lane & 15, l4 = lane >> 4;
  int rl = lane >> 2, cseg = (lane & 3) * 8;
  f32x4 acc[4][4] = {};

  for (int k0 = 0; k0 < K; k0 += 32) {
    #pragma unroll
    for (int q = 0; q < 2; ++q) {
      int rbase = (wv * 2 + q) * 16;
      gl_lds16(A + (size_t)(bm0 + rbase + rl) * K + k0 + cseg, As + rbase * 32);
      gl_lds16(B + (size_t)(bn0 + rbase + rl) * K + k0 + cseg, Bs + rbase * 32);
    }
    __syncthreads();   // compiler drains vmcnt before barrier
    bf16x8 af[4], bfm[4];
    #pragma unroll
    for (int m = 0; m < 4; ++m)
      af[m] = *reinterpret_cast<const bf16x8*>(As + (wr * 64 + m * 16 + l15) * 32 + l4 * 8);
    #pragma unroll
    for (int nn = 0; nn < 4; ++nn)
      bfm[nn] = *reinterpret_cast<const bf16x8*>(Bs + (wc * 64 + nn * 16 + l15) * 32 + l4 * 8);
    #pragma unroll
    for (int m = 0; m < 4; ++m)
      #pragma unroll
      for (int nn = 0; nn < 4; ++nn)
        acc[m][nn] = __builtin_amdgcn_mfma_f32_16x16x32_bf16(af[m], bfm[nn], acc[m][nn], 0, 0, 0);
    __syncthreads();
  }

  #pragma unroll
  for (int m = 0; m < 4; ++m) {
    int rbase = bm0 + wr * 64 + m * 16 + l4 * 4;
    #pragma unroll
    for (int nn = 0; nn < 4; ++nn) {
      int col = bn0 + wc * 64 + nn * 16 + l15;
      #pragma unroll
      for (int rr = 0; rr < 4; ++rr) {
        int row = rbase + rr;
        float v = acc[m][nn][rr];
        if (MODE == 0) {
          int bb = row >> 11, ww = row & 2047;
          int hh = col >> 6, kk = col & 63;
          ((u16*)C0)[(((size_t)(bb * NH + hh)) * SEQ + ww) * KD + kk] = f32_to_bf16(v);
        } else {
          ((float*)C0)[(size_t)row * N + col] = v;
        }
      }
    }
  }
}

// ---------------- qm = proj @ metric (per head, metric symmetric) ----------------
__launch_bounds__(256)
__global__ void qm_kernel(const u16* __restrict__ proj, const float* __restrict__ metric,
                          u16* __restrict__ qm) {
  int w0 = blockIdx.x * 32;
  int h = blockIdx.y, bb = blockIdx.z;
  __shared__ float M[64][65];
  __shared__ float Pr[32][64];
  int t = threadIdx.x;
  for (int i = t; i < 4096; i += 256) M[i >> 6][i & 63] = metric[(size_t)h * 4096 + i];
  const u16* pp = proj + (((size_t)bb * NH + h) * SEQ + w0) * KD;
  for (int i = t; i < 2048; i += 256) Pr[i >> 6][i & 63] = bf16_to_f32(pp[i]);
  __syncthreads();
  int kk = t & 63, g = t >> 6;
  #pragma unroll
  for (int r8 = 0; r8 < 8; ++r8) {
    int r = r8 * 4 + g;
    float acc = 0.f;
    #pragma unroll
    for (int l = 0; l < 64; ++l) acc += Pr[r][l] * M[kk][l];  // M symmetric
    qm[(((size_t)bb * NH + h) * SEQ + w0 + r) * KD + kk] = f32_to_bf16(acc);
  }
}

// ---------------- causal flash attention: warp-private kv-split, barrier-free loop ----
// grid: (32 bh, 64 chunk [LPT]), 256 threads = 4 warps.
// All warps share q rows [q0, q0+32); warp w owns a contiguous slice of the kv tiles.
// K tile == V tile == proj tile: one 8KB swizzled LDS buffer serves QK rows + PV columns.
__launch_bounds__(256)
__global__ void attn_kernel(const u16* __restrict__ qm, const u16* __restrict__ proj,
                            u16* __restrict__ nudged) {
  const int bh = blockIdx.x;
  const int bb = bh >> 4, h = bh & 15;
  const int chunk = 63 - (int)blockIdx.y;   // longest-first
  const int q0 = chunk * 32;
  const int t = threadIdx.x, wv = t >> 6, lane = t & 63;
  const int c = lane & 31, hi = lane >> 5;
  const int q_row = q0 + c;

  __shared__ __align__(16) u16 sm[32768];   // 64KB: 4 warp-slices of 16KB (2x4096 u16 dbuf)
  u16* slice = sm + wv * 8192;

  const size_t bho = (size_t)bh * SEQ * KD;
  const u16* kp = proj + bho;
  const u16* qmp = qm + bho;

  // Q fragments (same for all warps)
  bf16x8 qf[4];
  #pragma unroll
  for (int kc = 0; kc < 4; ++kc)
    qf[kc] = *reinterpret_cast<const bf16x8*>(qmp + (size_t)(q0 + c) * KD + kc * 16 + hi * 8);

  const int nt = (q0 + 32 + 63) / 64;       // kv tiles for this chunk
  const int bcnt = nt >> 2, brem = nt & 3;
  const int cnt = bcnt + (wv < brem);
  const int start = wv * bcnt + (wv < brem ? wv : brem);

  f32x16 o0 = {}, o1 = {};
  float mrow = -1e30f, lrow = 0.f;
  const float cl2 = 0.125f * 1.44269504088896f;   // 1/sqrt(64) * log2(e)

  auto issue = [&](int tile, int half) {
    const u16* src = kp + (size_t)tile * 64 * KD;
    u16* dst = slice + half * 4096;
    #pragma unroll
    for (int cl = 0; cl < 8; ++cl) {
      int rl = cl * 8 + (lane >> 3);                  // local kv row
      int col = ((lane & 7) * 8) ^ SW8(rl);           // inverse-swizzled source col
      gl_lds16(src + (size_t)rl * KD + col, dst + cl * 512);
    }
  };

  if (cnt > 0) issue(start, 0);
  for (int i = 0; i < cnt; ++i) {
    if (i + 1 < cnt) {
      issue(start + i + 1, (i + 1) & 1);
      asm volatile("s_waitcnt vmcnt(8)" ::: "memory");   // current tile's 8 loads done
    } else {
      asm volatile("s_waitcnt vmcnt(0)" ::: "memory");
    }
    __builtin_amdgcn_sched_barrier(0);
    const u16* Kt = slice + (i & 1) * 4096;
    const int j0 = (start + i) * 64;

    // S^T = K @ Q^T : rows=kv, cols=q (lane c owns q-col c)
    f32x16 s0 = {}, s1 = {};
    #pragma unroll
    for (int kc = 0; kc < 4; ++kc) {
      int colb = kc * 16 + hi * 8;
      bf16x8 a0 = *reinterpret_cast<const bf16x8*>(Kt + c * 64 + (colb ^ SW8(c)));
      bf16x8 a1 = *reinterpret_cast<const bf16x8*>(Kt + (c + 32) * 64 + (colb ^ SW8(c + 32)));
      s0 = __builtin_amdgcn_mfma_f32_32x32x16_bf16(a0, qf[kc], s0, 0, 0, 0);
      s1 = __builtin_amdgcn_mfma_f32_32x32x16_bf16(a1, qf[kc], s1, 0, 0, 0);
    }
    if (j0 + 63 > q0) {   // causal mask
      #pragma unroll
      for (int r = 0; r < 16; ++r) {
        int kvl = (r & 3) + 8 * (r >> 2) + 4 * hi;
        if (j0 + kvl      > q_row) s0[r] = -1e30f;
        if (j0 + 32 + kvl > q_row) s1[r] = -1e30f;
      }
    }
    // in-register row max + one cross-half swap
    float pmax = s0[0];
    #pragma unroll
    for (int r = 1; r < 16; ++r) pmax = fmaxf(pmax, s0[r]);
    #pragma unroll
    for (int r = 0; r < 16; ++r) pmax = fmaxf(pmax, s1[r]);
    pmax = fmaxf(pmax, __shfl_xor(pmax, 32));
    // T13 defer-max
    if (__any(pmax - mrow > 32.f)) {
      float mn = fmaxf(mrow, pmax);
      float alpha = exp2f((mrow - mn) * cl2);
      #pragma unroll
      for (int r = 0; r < 16; ++r) { o0[r] *= alpha; o1[r] *= alpha; }
      lrow *= alpha;
      mrow = mn;
    }
    const float mc = mrow * cl2;
    float rs = 0.f;
    #pragma unroll
    for (int r = 0; r < 16; ++r) { float p = exp2f(s0[r] * cl2 - mc); s0[r] = p; rs += p; }
    #pragma unroll
    for (int r = 0; r < 16; ++r) { float p = exp2f(s1[r] * cl2 - mc); s1[r] = p; rs += p; }
    rs += __shfl_xor(rs, 32);
    lrow += rs;

    // pack P to bf16 and exchange halves -> PA fragments pa[ks] = P[q=q0+c][16ks+8hi+0..7]
    u32 w[2][4][2];
    #pragma unroll
    for (int q4 = 0; q4 < 4; ++q4) {
      w[0][q4][0] = pack_bf16x2(s0[q4 * 4 + 0], s0[q4 * 4 + 1]);
      w[0][q4][1] = pack_bf16x2(s0[q4 * 4 + 2], s0[q4 * 4 + 3]);
      w[1][q4][0] = pack_bf16x2(s1[q4 * 4 + 0], s1[q4 * 4 + 1]);
      w[1][q4][1] = pack_bf16x2(s1[q4 * 4 + 2], s1[q4 * 4 + 3]);
    }
    bf16x8 pa[4];
    #pragma unroll
    for (int tt = 0; tt < 2; ++tt) {
      #pragma unroll
      for (int j = 0; j < 2; ++j) {
        int own = 2 * j + hi, send = 2 * j + (hi ^ 1);
        u32 ra = __shfl_xor(w[tt][send][0], 32);
        u32 rb = __shfl_xor(w[tt][send][1], 32);
        union { u32 u[4]; bf16x8 v; } pk;
        if (hi == 0) { pk.u[0] = w[tt][own][0]; pk.u[1] = w[tt][own][1]; pk.u[2] = ra; pk.u[3] = rb; }
        else         { pk.u[0] = ra; pk.u[1] = rb; pk.u[2] = w[tt][own][0]; pk.u[3] = w[tt][own][1]; }
        pa[tt * 2 + j] = pk.v;
      }
    }
    // O^T += V^T @ P^T : V^T A-frags via swizzled column reads of the SAME tile
    #pragma unroll
    for (int ks = 0; ks < 4; ++ks) {
      union { u16 hh[8]; bf16x8 v; } va0, va1;
      #pragma unroll
      for (int i2 = 0; i2 < 8; ++i2) {
        int kv = ks * 16 + hi * 8 + i2;
        int swz = SW8(kv);
        va0.hh[i2] = Kt[kv * 64 + (c ^ swz)];
        va1.hh[i2] = Kt[kv * 64 + ((c + 32) ^ swz)];
      }
      o0 = __builtin_amdgcn_mfma_f32_32x32x16_bf16(va0.v, pa[ks], o0, 0, 0, 0);
      o1 = __builtin_amdgcn_mfma_f32_32x32x16_bf16(va1.v, pa[ks], o1, 0, 0, 0);
    }
  }

  // write per-warp partials (O^T [64][32] padded 33, m, l) into own slice
  float* Ob = (float*)sm + wv * 4096;
  #pragma unroll
  for (int r = 0; r < 16; ++r) {
    int d = (r & 3) + 8 * (r >> 2) + 4 * hi;
    Ob[d * 33 + c] = o0[r];
    Ob[(d + 32) * 33 + c] = o1[r];
  }
  if (hi == 0) { Ob[2112 + c] = mrow; Ob[2144 + c] = lrow; }
  __syncthreads();

  // merge 4 partials + coalesced bf16 store
  {
    int q = t >> 3, dseg = t & 7;
    const float* b0 = (const float*)sm;
    float mw[4], lw[4];
    #pragma unroll
    for (int w2 = 0; w2 < 4; ++w2) {
      mw[w2] = b0[w2 * 4096 + 2112 + q];
      lw[w2] = b0[w2 * 4096 + 2144 + q];
    }
    float Mx = fmaxf(fmaxf(mw[0], mw[1]), fmaxf(mw[2], mw[3]));
    float sc[4], denom = 0.f;
    #pragma unroll
    for (int w2 = 0; w2 < 4; ++w2) {
      sc[w2] = exp2f((mw[w2] - Mx) * cl2);
      denom += lw[w2] * sc[w2];
    }
    float invd = 1.f / denom;
    u16 outv[8];
    #pragma unroll
    for (int i2 = 0; i2 < 8; ++i2) {
      int d = dseg * 8 + i2;
      float v = 0.f;
      #pragma unroll
      for (int w2 = 0; w2 < 4; ++w2) v += b0[w2 * 4096 + d * 33 + q] * sc[w2];
      outv[i2] = f32_to_bf16(v * invd);
    }
    u16* dstp = nudged + ((size_t)bb * SEQ + q0 + q) * CDIM + h * KD + dseg * 8;
    uint4 ov;
    ov.x = (u32)outv[0] | ((u32)outv[1] << 16);
    ov.y = (u32)outv[2] | ((u32)outv[3] << 16);
    ov.z = (u32)outv[4] | ((u32)outv[5] << 16);
    ov.w = (u32)outv[6] | ((u32)outv[7] << 16);
    *reinterpret_cast<uint4*>(dstp) = ov;
  }
}

// ---------------- host launch ----------------
extern "C" void kernel_launch(void* const* d_in, const int* in_sizes, int n_in,
                              void* d_out, int out_size, void* d_ws, size_t ws_size,
                              hipStream_t stream) {
  (void)in_sizes; (void)n_in; (void)out_size; (void)ws_size;
  const float* x      = (const float*)d_in[0];
  const float* Wproj  = (const float*)d_in[1];
  const float* premet = (const float*)d_in[2];
  const float* Wmix   = (const float*)d_in[3];

  char* w = (char*)d_ws;
  u16* x_bf   = (u16*)w;  w += (size_t)MROWS * CDIM * 2;        // 8 MB
  u16* wp_bf  = (u16*)w;  w += (size_t)CDIM * CDIM * 2;         // 2 MB
  u16* wm_bf  = (u16*)w;  w += (size_t)CDIM * CDIM * 2;         // 2 MB
  float* metric = (float*)w; w += (size_t)NH * KD * KD * 4;     // 256 KB
  u16* proj_bnwk = (u16*)w; w += (size_t)BATCH * NH * SEQ * KD * 2;  // 8 MB
  u16* qm        = (u16*)w; w += (size_t)BATCH * NH * SEQ * KD * 2;  // 8 MB
  u16* nudged    = (u16*)w; w += (size_t)MROWS * CDIM * 2;           // 8 MB

  hipLaunchKernelGGL(cvt_all, dim3(2048), dim3(256), 0, stream,
                     x, Wproj, Wmix, x_bf, wp_bf, wm_bf);
  hipLaunchKernelGGL(metric_kernel, dim3(NH), dim3(64), 0, stream, premet, metric);
  hipLaunchKernelGGL((gemm_xwt<0>), dim3(CDIM / 128, MROWS / 128), dim3(256), 0, stream,
                     x_bf, wp_bf, (void*)proj_bnwk, MROWS, CDIM, CDIM);
  hipLaunchKernelGGL(qm_kernel, dim3(SEQ / 32, NH, BATCH), dim3(256), 0, stream,
                     proj_bnwk, metric, qm);
  hipLaunchKernelGGL(attn_kernel, dim3(32, 64), dim3(256), 0, stream,
                     qm, proj_bnwk, nudged);
  hipLaunchKernelGGL((gemm_xwt<1>), dim3(CDIM / 128, MROWS / 128), dim3(256), 0, stream,
                     nudged, wm_bf, d_out, MROWS, CDIM, CDIM);
}

// Round 4
// 235.970 us; speedup vs baseline: 1.1327x; 1.0352x over previous
//
#include <hip/hip_runtime.h>
#include <stdint.h>
#include <stddef.h>

typedef unsigned short u16;
typedef unsigned int u32;
typedef __attribute__((ext_vector_type(8))) __bf16 bf16x8;
typedef __attribute__((ext_vector_type(4))) float f32x4;
typedef __attribute__((ext_vector_type(16))) float f32x16;

#define DEV __device__ __forceinline__

// ---- problem dims (hardcoded per reference) ----
#define BATCH 2
#define SEQ   2048
#define CDIM  1024
#define NH    16
#define KD    64
#define MROWS (BATCH * SEQ)   // 4096
#define NX (MROWS * CDIM)     // 4194304
#define NW (CDIM * CDIM)      // 1048576

DEV u16 f32_to_bf16(float f) {
  union { float f; unsigned u; } v; v.f = f;
  return (u16)((v.u + 0x7fffu + ((v.u >> 16) & 1u)) >> 16);
}
DEV float bf16_to_f32(u16 h) {
  union { unsigned u; float f; } v; v.u = ((unsigned)h) << 16;
  return v.f;
}
DEV u32 pack_bf16x2(float a, float b) {
  union { __bf16 h[2]; u32 u; } r;
  r.h[0] = (__bf16)a; r.h[1] = (__bf16)b;
  return r.u;
}

// XOR swizzle in u16 units (8-granular) — used by the GEMM staging only
#define SW8(r) ((((r) ^ ((r) >> 3)) & 7) << 3)

// async global->LDS, 16B per lane
DEV void gl_lds16(const u16* g, u16* l) {
  __builtin_amdgcn_global_load_lds(
      (const __attribute__((address_space(1))) void*)(g),
      (__attribute__((address_space(3))) void*)(l), 16, 0, 0);
}

// ---------------- fused f32 -> bf16 convert (x, W_proj, W_mix) ----------------
__global__ void cvt_all(const float* __restrict__ x, const float* __restrict__ wp,
                        const float* __restrict__ wm,
                        u16* __restrict__ xb, u16* __restrict__ wpb, u16* __restrict__ wmb) {
  int total4 = (NX + 2 * NW) >> 2;
  for (int i4 = blockIdx.x * blockDim.x + threadIdx.x; i4 < total4;
       i4 += gridDim.x * blockDim.x) {
    int i = i4 << 2;
    const float* src; u16* dst; int off;
    if (i < NX)           { src = x;  dst = xb;  off = i; }
    else if (i < NX + NW) { src = wp; dst = wpb; off = i - NX; }
    else                  { src = wm; dst = wmb; off = i - NX - NW; }
    float4 v = *reinterpret_cast<const float4*>(src + off);
    ushort4 o;
    o.x = f32_to_bf16(v.x); o.y = f32_to_bf16(v.y);
    o.z = f32_to_bf16(v.z); o.w = f32_to_bf16(v.w);
    *reinterpret_cast<ushort4*>(dst + off) = o;
  }
}

// ---------------- metric = (row-softmax of tril(pm)/8) @ P^T ----------------
// 16 blocks x 256 threads: wave 0 does the (tiny) row softmaxes, all 256 do P@P^T.
__global__ void metric_kernel(const float* __restrict__ pm, float* __restrict__ metric) {
  int h = blockIdx.x, t = threadIdx.x;
  __shared__ float P[64][65];
  if (t < 64) {
    int i = t;
    const float* row = pm + (size_t)(h * 64 + i) * 64;
    float mx = -1e30f;
    for (int j = 0; j <= i; ++j) mx = fmaxf(mx, row[j] * 0.125f);
    float s = 0.f;
    for (int j = 0; j <= i; ++j) { float e = expf(row[j] * 0.125f - mx); P[i][j] = e; s += e; }
    float inv = 1.f / s;
    for (int j = 0; j <= i; ++j) P[i][j] *= inv;
    for (int j = i + 1; j < 64; ++j) P[i][j] = 0.f;
  }
  __syncthreads();
  int i = t >> 2;
  int jb = (t & 3) * 16;
  for (int jj = 0; jj < 16; ++jj) {
    int j = jb + jj;
    float acc = 0.f;
    #pragma unroll
    for (int l = 0; l < 64; ++l) acc += P[i][l] * P[j][l];
    metric[(size_t)h * 4096 + i * 64 + j] = acc;
  }
}

// ---------------- bf16 MFMA GEMM: C = A @ B^T, global_load_lds staging ----------------
// MODE 0: write proj_bnwk bf16;  MODE 1: write f32 C0[M][N]
template <int MODE>
__launch_bounds__(256)
__global__ void gemm_xwt(const u16* __restrict__ A, const u16* __restrict__ B,
                         void* __restrict__ C0, int M, int N, int K) {
  __shared__ __align__(16) u16 As[128 * 32];
  __shared__ __align__(16) u16 Bs[128 * 32];
  int bm0 = blockIdx.y * 128, bn0 = blockIdx.x * 128;
  int t = threadIdx.x, wv = t >> 6, lane = t & 63;
  int wr = wv >> 1, wc = wv & 1;
  int l15 = lane & 15, l4 = lane >> 4;
  int rl = lane >> 2, cseg = (lane & 3) * 8;
  f32x4 acc[4][4] = {};

  for (int k0 = 0; k0 < K; k0 += 32) {
    #pragma unroll
    for (int q = 0; q < 2; ++q) {
      int rbase = (wv * 2 + q) * 16;
      gl_lds16(A + (size_t)(bm0 + rbase + rl) * K + k0 + cseg, As + rbase * 32);
      gl_lds16(B + (size_t)(bn0 + rbase + rl) * K + k0 + cseg, Bs + rbase * 32);
    }
    __syncthreads();
    bf16x8 af[4], bfm[4];
    #pragma unroll
    for (int m = 0; m < 4; ++m)
      af[m] = *reinterpret_cast<const bf16x8*>(As + (wr * 64 + m * 16 + l15) * 32 + l4 * 8);
    #pragma unroll
    for (int nn = 0; nn < 4; ++nn)
      bfm[nn] = *reinterpret_cast<const bf16x8*>(Bs + (wc * 64 + nn * 16 + l15) * 32 + l4 * 8);
    #pragma unroll
    for (int m = 0; m < 4; ++m)
      #pragma unroll
      for (int nn = 0; nn < 4; ++nn)
        acc[m][nn] = __builtin_amdgcn_mfma_f32_16x16x32_bf16(af[m], bfm[nn], acc[m][nn], 0, 0, 0);
    __syncthreads();
  }

  #pragma unroll
  for (int m = 0; m < 4; ++m) {
    int rbase = bm0 + wr * 64 + m * 16 + l4 * 4;
    #pragma unroll
    for (int nn = 0; nn < 4; ++nn) {
      int col = bn0 + wc * 64 + nn * 16 + l15;
      #pragma unroll
      for (int rr = 0; rr < 4; ++rr) {
        int row = rbase + rr;
        float v = acc[m][nn][rr];
        if (MODE == 0) {
          int bb = row >> 11, ww = row & 2047;
          int hh = col >> 6, kk = col & 63;
          ((u16*)C0)[(((size_t)(bb * NH + hh)) * SEQ + ww) * KD + kk] = f32_to_bf16(v);
        } else {
          ((float*)C0)[(size_t)row * N + col] = v;
        }
      }
    }
  }
}

// ---------------- qm = proj @ metric (per head); also emits projT [bh][d][w] ------
__launch_bounds__(256)
__global__ void qm_kernel(const u16* __restrict__ proj, const float* __restrict__ metric,
                          u16* __restrict__ qm, u16* __restrict__ projT) {
  int w0 = blockIdx.x * 32;
  int h = blockIdx.y, bb = blockIdx.z;
  __shared__ float M[64][65];
  __shared__ float Pr[32][64];
  int t = threadIdx.x;
  for (int i = t; i < 4096; i += 256) M[i >> 6][i & 63] = metric[(size_t)h * 4096 + i];
  const size_t bh = (size_t)bb * NH + h;
  const u16* pp = proj + (bh * SEQ + w0) * KD;
  for (int i = t; i < 2048; i += 256) Pr[i >> 6][i & 63] = bf16_to_f32(pp[i]);
  __syncthreads();
  int kk = t & 63, g = t >> 6;
  #pragma unroll
  for (int r8 = 0; r8 < 8; ++r8) {
    int r = r8 * 4 + g;
    float acc = 0.f;
    #pragma unroll
    for (int l = 0; l < 64; ++l) acc += Pr[r][l] * M[kk][l];  // M symmetric
    qm[(bh * SEQ + w0 + r) * KD + kk] = f32_to_bf16(acc);
  }
  // emit transposed V: projT[bh][d][w0 + ws8*8 .. +8]
  {
    int d = t & 63, ws8 = t >> 6;
    u16 tmp[8];
    #pragma unroll
    for (int i2 = 0; i2 < 8; ++i2) tmp[i2] = f32_to_bf16(Pr[ws8 * 8 + i2][d]);
    uint4 ov;
    ov.x = (u32)tmp[0] | ((u32)tmp[1] << 16);
    ov.y = (u32)tmp[2] | ((u32)tmp[3] << 16);
    ov.z = (u32)tmp[4] | ((u32)tmp[5] << 16);
    ov.w = (u32)tmp[6] | ((u32)tmp[7] << 16);
    *reinterpret_cast<uint4*>(projT + (bh * KD + d) * SEQ + w0 + ws8 * 8) = ov;
  }
}

// ---------------- causal flash attention: warp-independent, zero LDS, zero barriers --
// grid (32 bh, 16), 256 threads = 4 warps; warp wv owns chunk = 63-(4*by+wv), rows q0..q0+31.
// All MFMA operands are direct 16B global loads (K/V are L2-resident: 512KB/head).
__launch_bounds__(256)
__global__ void attn_kernel(const u16* __restrict__ qm, const u16* __restrict__ proj,
                            const u16* __restrict__ projT, u16* __restrict__ nudged) {
  const int bh = blockIdx.x;
  const int bb = bh >> 4, h = bh & 15;
  const int t = threadIdx.x, wv = t >> 6, lane = t & 63;
  const int c = lane & 31, hi = lane >> 5;
  const int chunk = 63 - ((int)blockIdx.y * 4 + wv);   // longest-first
  const int q0 = chunk * 32;
  const int q_row = q0 + c;

  const size_t bho = (size_t)bh * SEQ * KD;
  const u16* kp  = proj + bho;
  const u16* qmp = qm + bho;
  const u16* vtp = projT + bho;

  // Q fragments (B-operand), held for the whole loop
  bf16x8 qf[4];
  #pragma unroll
  for (int kc = 0; kc < 4; ++kc)
    qf[kc] = *reinterpret_cast<const bf16x8*>(qmp + (size_t)q_row * KD + kc * 16 + hi * 8);

  const int nt = (q0 + 32 + 63) >> 6;

  f32x16 o0 = {}, o1 = {};
  float mrow = -1e30f, lrow = 0.f;
  const float cl2 = 0.125f * 1.44269504088896f;   // 1/sqrt(64) * log2(e)

  // K-frags (A-operand rows j0+c, j0+32+c) and V^T-frags (A-operand rows d=c, d=c+32)
  bf16x8 kf0[4], kf1[4], vf0[4], vf1[4];
  #pragma unroll
  for (int kc = 0; kc < 4; ++kc) {
    kf0[kc] = *reinterpret_cast<const bf16x8*>(kp + (size_t)c * KD + kc * 16 + hi * 8);
    kf1[kc] = *reinterpret_cast<const bf16x8*>(kp + (size_t)(c + 32) * KD + kc * 16 + hi * 8);
    vf0[kc] = *reinterpret_cast<const bf16x8*>(vtp + (size_t)c * SEQ + kc * 16 + hi * 8);
    vf1[kc] = *reinterpret_cast<const bf16x8*>(vtp + (size_t)(c + 32) * SEQ + kc * 16 + hi * 8);
  }

  for (int i = 0; i < nt; ++i) {
    const int j0 = i * 64;
    // S^T = K @ qm^T : rows=kv, cols=q (lane c owns q-col c)
    f32x16 s0 = {}, s1 = {};
    #pragma unroll
    for (int kc = 0; kc < 4; ++kc) {
      s0 = __builtin_amdgcn_mfma_f32_32x32x16_bf16(kf0[kc], qf[kc], s0, 0, 0, 0);
      s1 = __builtin_amdgcn_mfma_f32_32x32x16_bf16(kf1[kc], qf[kc], s1, 0, 0, 0);
    }
    // prefetch next K tile (hidden under softmax + PV)
    if (i + 1 < nt) {
      const u16* kn = kp + (size_t)(j0 + 64) * KD;
      #pragma unroll
      for (int kc = 0; kc < 4; ++kc) {
        kf0[kc] = *reinterpret_cast<const bf16x8*>(kn + (size_t)c * KD + kc * 16 + hi * 8);
        kf1[kc] = *reinterpret_cast<const bf16x8*>(kn + (size_t)(c + 32) * KD + kc * 16 + hi * 8);
      }
    }
    // causal mask (uniform branch; only diagonal-overlapping tiles)
    if (j0 + 63 > q0) {
      #pragma unroll
      for (int r = 0; r < 16; ++r) {
        int kvl = (r & 3) + 8 * (r >> 2) + 4 * hi;
        if (j0 + kvl      > q_row) s0[r] = -1e30f;
        if (j0 + 32 + kvl > q_row) s1[r] = -1e30f;
      }
    }
    // row max: depth-6 tree + one cross-half swap
    float mx[16];
    #pragma unroll
    for (int r = 0; r < 16; ++r) mx[r] = fmaxf(s0[r], s1[r]);
    #pragma unroll
    for (int st = 8; st >= 1; st >>= 1)
      #pragma unroll
      for (int r = 0; r < st; ++r) mx[r] = fmaxf(mx[r], mx[r + st]);
    float pmax = fmaxf(mx[0], __shfl_xor(mx[0], 32));
    // T13 defer-max: rescale only when max grew past headroom
    if (__any(pmax - mrow > 32.f)) {
      float mn = fmaxf(mrow, pmax);
      float alpha = exp2f((mrow - mn) * cl2);
      #pragma unroll
      for (int r = 0; r < 16; ++r) { o0[r] *= alpha; o1[r] *= alpha; }
      lrow *= alpha;
      mrow = mn;
    }
    const float mc = mrow * cl2;
    float sv[16];
    #pragma unroll
    for (int r = 0; r < 16; ++r) {
      float p0 = exp2f(s0[r] * cl2 - mc); s0[r] = p0;
      float p1 = exp2f(s1[r] * cl2 - mc); s1[r] = p1;
      sv[r] = p0 + p1;
    }
    #pragma unroll
    for (int st = 8; st >= 1; st >>= 1)
      #pragma unroll
      for (int r = 0; r < st; ++r) sv[r] += sv[r + st];
    float rs = sv[0] + __shfl_xor(sv[0], 32);
    lrow += rs;

    // pack P to bf16, exchange halves -> PA frags pa[ks] = P[q=q0+c][16ks+8hi+0..7]
    u32 w[2][4][2];
    #pragma unroll
    for (int q4 = 0; q4 < 4; ++q4) {
      w[0][q4][0] = pack_bf16x2(s0[q4 * 4 + 0], s0[q4 * 4 + 1]);
      w[0][q4][1] = pack_bf16x2(s0[q4 * 4 + 2], s0[q4 * 4 + 3]);
      w[1][q4][0] = pack_bf16x2(s1[q4 * 4 + 0], s1[q4 * 4 + 1]);
      w[1][q4][1] = pack_bf16x2(s1[q4 * 4 + 2], s1[q4 * 4 + 3]);
    }
    bf16x8 pa[4];
    #pragma unroll
    for (int tt = 0; tt < 2; ++tt) {
      #pragma unroll
      for (int j = 0; j < 2; ++j) {
        int own = 2 * j + hi, send = 2 * j + (hi ^ 1);
        u32 ra = __shfl_xor(w[tt][send][0], 32);
        u32 rb = __shfl_xor(w[tt][send][1], 32);
        union { u32 u[4]; bf16x8 v; } pk;
        if (hi == 0) { pk.u[0] = w[tt][own][0]; pk.u[1] = w[tt][own][1]; pk.u[2] = ra; pk.u[3] = rb; }
        else         { pk.u[0] = ra; pk.u[1] = rb; pk.u[2] = w[tt][own][0]; pk.u[3] = w[tt][own][1]; }
        pa[tt * 2 + j] = pk.v;
      }
    }
    // O^T += V^T @ P^T (stats stay lane-local)
    #pragma unroll
    for (int ks = 0; ks < 4; ++ks) {
      o0 = __builtin_amdgcn_mfma_f32_32x32x16_bf16(vf0[ks], pa[ks], o0, 0, 0, 0);
      o1 = __builtin_amdgcn_mfma_f32_32x32x16_bf16(vf1[ks], pa[ks], o1, 0, 0, 0);
    }
    // prefetch next V^T tile (hidden under next QK + softmax)
    if (i + 1 < nt) {
      const u16* vn = vtp + j0 + 64;
      #pragma unroll
      for (int ks = 0; ks < 4; ++ks) {
        vf0[ks] = *reinterpret_cast<const bf16x8*>(vn + (size_t)c * SEQ + ks * 16 + hi * 8);
        vf1[ks] = *reinterpret_cast<const bf16x8*>(vn + (size_t)(c + 32) * SEQ + ks * 16 + hi * 8);
      }
    }
  }

  // epilogue: normalize, pack, store (8B per lane per group; rows = q0+c)
  float inv = 1.f / lrow;
  u16* orow = nudged + ((size_t)bb * SEQ + q_row) * CDIM + h * KD;
  #pragma unroll
  for (int g = 0; g < 4; ++g) {
    int d0 = g * 8 + hi * 4;
    uint2 a, b2;
    a.x  = pack_bf16x2(o0[g * 4 + 0] * inv, o0[g * 4 + 1] * inv);
    a.y  = pack_bf16x2(o0[g * 4 + 2] * inv, o0[g * 4 + 3] * inv);
    b2.x = pack_bf16x2(o1[g * 4 + 0] * inv, o1[g * 4 + 1] * inv);
    b2.y = pack_bf16x2(o1[g * 4 + 2] * inv, o1[g * 4 + 3] * inv);
    *reinterpret_cast<uint2*>(orow + d0)      = a;
    *reinterpret_cast<uint2*>(orow + 32 + d0) = b2;
  }
}

// ---------------- host launch ----------------
extern "C" void kernel_launch(void* const* d_in, const int* in_sizes, int n_in,
                              void* d_out, int out_size, void* d_ws, size_t ws_size,
                              hipStream_t stream) {
  (void)in_sizes; (void)n_in; (void)out_size; (void)ws_size;
  const float* x      = (const float*)d_in[0];
  const float* Wproj  = (const float*)d_in[1];
  const float* premet = (const float*)d_in[2];
  const float* Wmix   = (const float*)d_in[3];

  char* w = (char*)d_ws;
  u16* x_bf   = (u16*)w;  w += (size_t)MROWS * CDIM * 2;        // 8 MB
  u16* wp_bf  = (u16*)w;  w += (size_t)CDIM * CDIM * 2;         // 2 MB
  u16* wm_bf  = (u16*)w;  w += (size_t)CDIM * CDIM * 2;         // 2 MB
  float* metric = (float*)w; w += (size_t)NH * KD * KD * 4;     // 256 KB
  u16* proj_bnwk = (u16*)w; w += (size_t)BATCH * NH * SEQ * KD * 2;  // 8 MB
  u16* projT     = (u16*)w; w += (size_t)BATCH * NH * KD * SEQ * 2;  // 8 MB
  u16* qm        = (u16*)w; w += (size_t)BATCH * NH * SEQ * KD * 2;  // 8 MB
  u16* nudged    = (u16*)w; w += (size_t)MROWS * CDIM * 2;           // 8 MB

  hipLaunchKernelGGL(cvt_all, dim3(2048), dim3(256), 0, stream,
                     x, Wproj, Wmix, x_bf, wp_bf, wm_bf);
  hipLaunchKernelGGL(metric_kernel, dim3(NH), dim3(256), 0, stream, premet, metric);
  hipLaunchKernelGGL((gemm_xwt<0>), dim3(CDIM / 128, MROWS / 128), dim3(256), 0, stream,
                     x_bf, wp_bf, (void*)proj_bnwk, MROWS, CDIM, CDIM);
  hipLaunchKernelGGL(qm_kernel, dim3(SEQ / 32, NH, BATCH), dim3(256), 0, stream,
                     proj_bnwk, metric, qm, projT);
  hipLaunchKernelGGL(attn_kernel, dim3(32, 16), dim3(256), 0, stream,
                     qm, proj_bnwk, projT, nudged);
  hipLaunchKernelGGL((gemm_xwt<1>), dim3(CDIM / 128, MROWS / 128), dim3(256), 0, stream,
                     nudged, wm_bf, d_out, MROWS, CDIM, CDIM);
}